// Round 6
// baseline (793.205 us; speedup 1.0000x reference)
//
#include <hip/hip_runtime.h>
#include <cstdint>

// ---------------------------------------------------------------------------
// ConvModule: LN -> GEMM(512->1024)+SiLU -> conv K=5 (1024->1024) -> GLU ->
//             BN -> GEMM(512->512).  B=16, T=1024, C=512. fp32 I/O, bf16 MFMA.
// Round 6: barrier-free, LDS-free main loops. A/B frags direct from global
// (K-contiguous), depth-2 register rotation prefetch (~160cyc cover), 64x256
// tile with waves side-by-side in N (A shared via L1, no dup B loads), XCD-
// pinned n-slices. LDS only for private coalesced epilogue transpose.
// R5 lesson: >2-slot register prefetch spills (WRITE_SIZE 7x) — keep depth 2.
// ---------------------------------------------------------------------------

#define NB    16
#define TT    1024
#define CC    512
#define C2    1024
#define TPAD  1028        // T + 4 pad rows (2 each side) per batch

typedef unsigned short u16;
typedef short bf16x8 __attribute__((ext_vector_type(8)));
typedef float f32x4  __attribute__((ext_vector_type(4)));

__device__ __forceinline__ float bf2f(u16 u) {
  union { unsigned int i; float f; } v; v.i = ((unsigned int)u) << 16; return v.f;
}
__device__ __forceinline__ u16 f2bf(float f) {
  union { float f; unsigned int i; } v; v.f = f;
  unsigned int x = v.i;
  return (u16)((x + 0x7fffu + ((x >> 16) & 1u)) >> 16);  // RNE
}

// ---------------------------------------------------------------------------
// prep: cvt w1 (fp32->bf16), cvt w3, zero h1p pad rows — one launch
__global__ __launch_bounds__(256) void prep_k(
    const float* __restrict__ w1, u16* __restrict__ w1b,
    const float* __restrict__ w3, u16* __restrict__ w3b,
    u16* __restrict__ h1p) {
  const int b = blockIdx.x;
  if (b < 512) {                       // w1: 524288 elems
    const int i = (b * 256 + threadIdx.x) * 4;
    float4 v = *(const float4*)(w1 + i);
    u16 o[4] = { f2bf(v.x), f2bf(v.y), f2bf(v.z), f2bf(v.w) };
    *(uint2*)(w1b + i) = *(const uint2*)o;
  } else if (b < 768) {                // w3: 262144 elems
    const int i = ((b - 512) * 256 + threadIdx.x) * 4;
    float4 v = *(const float4*)(w3 + i);
    u16 o[4] = { f2bf(v.x), f2bf(v.y), f2bf(v.z), f2bf(v.w) };
    *(uint2*)(w3b + i) = *(const uint2*)o;
  } else {                             // zero pads: 32 blocks, 8 elems/thread
    const int idx = (b - 768) * 256 + threadIdx.x;
    const int bb  = idx >> 9;
    const int rem = idx & 511;
    const int ri  = rem >> 7;
    const int c8  = (rem & 127) * 8;
    const int row = bb * TPAD + (ri < 2 ? ri : 1024 + ri);   // 0,1,1026,1027
    uint4 z = make_uint4(0u, 0u, 0u, 0u);
    *(uint4*)(h1p + (size_t)row * C2 + c8) = z;
  }
}

// ---------------------------------------------------------------------------
// w2 fp32 (K, I, O) -> w2t bf16 (K, O, I)
__global__ void transpose_w2(const float* __restrict__ w2, u16* __restrict__ w2t) {
  __shared__ u16 t[64][65];
  const int k  = blockIdx.z;
  const int i0 = blockIdx.x * 64, o0 = blockIdx.y * 64;
  const int tx = threadIdx.x, ty = threadIdx.y;
  for (int r = ty; r < 64; r += 4)
    t[r][tx] = f2bf(w2[((size_t)(k * C2) + i0 + r) * C2 + o0 + tx]);
  __syncthreads();
  for (int r = ty; r < 64; r += 4)
    w2t[((size_t)(k * C2) + o0 + r) * C2 + i0 + tx] = t[tx][r];
}

// ---------------------------------------------------------------------------
__global__ __launch_bounds__(256) void layernorm_k(
    const float* __restrict__ x, const float* __restrict__ lng,
    const float* __restrict__ lnb, u16* __restrict__ out) {
  const int tok  = blockIdx.x * 4 + (threadIdx.x >> 6);
  const int lane = threadIdx.x & 63;
  const float* xp = x + (size_t)tok * CC + lane * 8;
  float f[8];
  *(float4*)(f)     = *(const float4*)(xp);
  *(float4*)(f + 4) = *(const float4*)(xp + 4);
  float s = 0.f, s2 = 0.f;
#pragma unroll
  for (int j = 0; j < 8; j++) { s += f[j]; s2 += f[j] * f[j]; }
#pragma unroll
  for (int m = 32; m >= 1; m >>= 1) { s += __shfl_xor(s, m, 64); s2 += __shfl_xor(s2, m, 64); }
  const float mu  = s  * (1.f / 512.f);
  const float var = s2 * (1.f / 512.f) - mu * mu;
  const float rs  = rsqrtf(var + 1e-5f);
  u16 ov[8];
#pragma unroll
  for (int j = 0; j < 8; j++) {
    const int c = lane * 8 + j;
    ov[j] = f2bf((f[j] - mu) * rs * lng[c] + lnb[c]);
  }
  *(uint4*)(out + (size_t)tok * CC + lane * 8) = *(const uint4*)ov;
}

// ---------------------------------------------------------------------------
// GEMM out[m,n] = sum_k A[m,k]*Bt[n,k] + bias[n].
// Barrier-free / LDS-free loop: tile 64M x 256N, 4 waves side-by-side in N.
// A,B frags direct global b128, depth-2 rotation prefetch.
// EPI 0: SiLU, bf16 -> h1p padded rows.  EPI 1: fp32 -> out (ld CC).
template <int EPI>
__global__ __launch_bounds__(256, 2) void gemm_bt(
    const u16* __restrict__ A, const u16* __restrict__ Bt,
    const float* __restrict__ bias, void* __restrict__ outv,
    const int Kd, const int ldA) {
  __shared__ __align__(16) u16 smem[18432];     // epilogue only (4608/wave)
  const int tid  = threadIdx.x;
  const int m0   = blockIdx.y * 64;
  const int wave = tid >> 6, lane = tid & 63;
  const int n0   = blockIdx.x * 256 + wave * 64;   // per-wave col base
  const int quad = lane >> 4, l16 = lane & 15;
  const int J = Kd >> 5;

  const u16* Ab = A  + (size_t)(m0 + l16) * ldA + quad * 8;
  const u16* Bb = Bt + (size_t)(n0 + l16) * Kd  + quad * 8;

  f32x4 acc[4][4] = {};
  bf16x8 Aq[2][4], Bq[2][4];
#pragma unroll
  for (int i = 0; i < 4; i++) {
    Aq[0][i] = *(const bf16x8*)(Ab + (size_t)i * 16 * ldA);
    Bq[0][i] = *(const bf16x8*)(Bb + (size_t)i * 16 * Kd);
  }
#pragma unroll
  for (int i = 0; i < 4; i++) {
    Aq[1][i] = *(const bf16x8*)(Ab + (size_t)i * 16 * ldA + 32);
    Bq[1][i] = *(const bf16x8*)(Bb + (size_t)i * 16 * Kd  + 32);
  }

#pragma unroll 1
  for (int jj = 0; jj < J; jj += 2) {
#pragma unroll
    for (int h = 0; h < 2; h++) {
      const int j = jj + h;
#pragma unroll
      for (int mi = 0; mi < 4; mi++)
#pragma unroll
        for (int ni = 0; ni < 4; ni++)
          acc[mi][ni] = __builtin_amdgcn_mfma_f32_16x16x32_bf16(
              Aq[h][mi], Bq[h][ni], acc[mi][ni], 0, 0, 0);
      const int j2 = (j + 2 < J) ? j + 2 : 0;   // clamped tail prefetch
      const int k2 = j2 * 32;
#pragma unroll
      for (int i = 0; i < 4; i++) {
        Aq[h][i] = *(const bf16x8*)(Ab + (size_t)i * 16 * ldA + k2);
        Bq[h][i] = *(const bf16x8*)(Bb + (size_t)i * 16 * Kd  + k2);
      }
    }
  }

  float bv[4];
#pragma unroll
  for (int ni = 0; ni < 4; ni++) bv[ni] = bias[n0 + ni * 16 + l16];

  if (EPI == 0) {
    u16* epi = smem + wave * 4608;       // 64 x 72 u16, private
#pragma unroll
    for (int mi = 0; mi < 4; mi++)
#pragma unroll
      for (int ni = 0; ni < 4; ni++)
#pragma unroll
        for (int r = 0; r < 4; r++) {
          float v = acc[mi][ni][r] + bv[ni];
          v = v / (1.f + __expf(-v));    // SiLU
          epi[(mi * 16 + quad * 4 + r) * 72 + ni * 16 + l16] = f2bf(v);
        }
    u16* h1p = (u16*)outv;
#pragma unroll
    for (int p = 0; p < 8; p++) {
      const int rrow = p * 8 + (lane >> 3);
      const int colb = (lane & 7) * 8;
      uint4 v = *(const uint4*)(epi + rrow * 72 + colb);
      const int rr = m0 + rrow;
      const int bb = rr >> 10, tt = rr & 1023;
      *(uint4*)(h1p + (size_t)(bb * TPAD + tt + 2) * C2 + n0 + colb) = v;
    }
  } else {
    float* fepi = (float*)(smem + wave * 4608);   // 2 x (16 x 68) f32
    float* outf = (float*)outv;
#pragma unroll
    for (int mi = 0; mi < 4; mi++) {
      float* fp = fepi + (mi & 1) * 1088;
#pragma unroll
      for (int ni = 0; ni < 4; ni++)
#pragma unroll
        for (int r = 0; r < 4; r++)
          fp[(quad * 4 + r) * 68 + ni * 16 + l16] = acc[mi][ni][r] + bv[ni];
#pragma unroll
      for (int p = 0; p < 4; p++) {
        const int rrow = p * 4 + (lane >> 4);
        const int col  = (lane & 15) * 4;
        float4 v = *(const float4*)(fp + rrow * 68 + col);
        *(float4*)(outf + (size_t)(m0 + mi * 16 + rrow) * CC + n0 + col) = v;
      }
    }
  }
}

// ---------------------------------------------------------------------------
// 5-tap conv, barrier-free / LDS-free: A frags direct global (tap overlap via
// L1), B frags direct global (XCD-pinned L2 slice). Depth-2 stage rotation
// over linear stages s = j*5 + k (32 chunks x 5 taps).
__global__ __launch_bounds__(256, 2) void conv5_mfma(
    const u16* __restrict__ h1p, const u16* __restrict__ w2t,
    const float* __restrict__ b2, u16* __restrict__ out) {
  __shared__ __align__(16) u16 smem[18432];     // epilogue only
  const int tid = threadIdx.x;
  const int mt  = blockIdx.y;                   // 0..255
  const int wave = tid >> 6, lane = tid & 63;
  const int n0  = blockIdx.x * 256 + wave * 64; // per-wave col base
  const int bb  = mt >> 4;
  const int t0  = (mt & 15) * 64;
  const size_t arow0 = (size_t)bb * TPAD + t0;
  const int quad = lane >> 4, l16 = lane & 15;

  const u16* Ab = h1p + (arow0 + l16) * C2 + quad * 8;        // + (i*16+k)*C2 + i0
  const u16* Bb = w2t + (size_t)(n0 + l16) * C2 + quad * 8;   // + k*C2*C2 + i*16*C2 + i0

  f32x4 acc[4][4] = {};
  bf16x8 Aq[2][4], Bq[2][4];
  // prologue: stage 0 = (chunk 0, tap 0), stage 1 = (chunk 0, tap 1)
#pragma unroll
  for (int i = 0; i < 4; i++) {
    Aq[0][i] = *(const bf16x8*)(Ab + (size_t)(i * 16 + 0) * C2);
    Bq[0][i] = *(const bf16x8*)(Bb + (size_t)i * 16 * C2);
  }
#pragma unroll
  for (int i = 0; i < 4; i++) {
    Aq[1][i] = *(const bf16x8*)(Ab + (size_t)(i * 16 + 1) * C2);
    Bq[1][i] = *(const bf16x8*)(Bb + (size_t)C2 * C2 + (size_t)i * 16 * C2);
  }

#pragma unroll 1
  for (int jj = 0; jj < 32; jj += 2) {
#pragma unroll
    for (int h = 0; h < 2; h++) {               // j = jj+h; stage parity (k+h)&1
      const int j = jj + h;
#pragma unroll
      for (int k = 0; k < 5; k++) {
        const int slot = (k + h) & 1;
#pragma unroll
        for (int mi = 0; mi < 4; mi++)
#pragma unroll
          for (int ni = 0; ni < 4; ni++)
            acc[mi][ni] = __builtin_amdgcn_mfma_f32_16x16x32_bf16(
                Aq[slot][mi], Bq[slot][ni], acc[mi][ni], 0, 0, 0);
        // prefetch stage s+2: (j, k+2) if k<3 else ((j+1)&31, k-3)
        const int k2  = (k < 3) ? k + 2 : k - 3;
        const int c2  = (k < 3) ? j : ((j + 1) & 31);
        const int io2 = c2 * 32;
#pragma unroll
        for (int i = 0; i < 4; i++) {
          Aq[slot][i] = *(const bf16x8*)(Ab + (size_t)(i * 16 + k2) * C2 + io2);
          Bq[slot][i] = *(const bf16x8*)(Bb + (size_t)k2 * C2 * C2 +
                                         (size_t)i * 16 * C2 + io2);
        }
      }
    }
  }

  float bv[4];
#pragma unroll
  for (int ni = 0; ni < 4; ni++) bv[ni] = b2[n0 + ni * 16 + l16];

  u16* epi = smem + wave * 4608;         // 64 x 72 u16, private
#pragma unroll
  for (int mi = 0; mi < 4; mi++)
#pragma unroll
    for (int ni = 0; ni < 4; ni++)
#pragma unroll
      for (int r = 0; r < 4; r++)
        epi[(mi * 16 + quad * 4 + r) * 72 + ni * 16 + l16] = f2bf(acc[mi][ni][r] + bv[ni]);

  const size_t orow0 = (size_t)bb * TT + t0;
#pragma unroll
  for (int p = 0; p < 8; p++) {
    const int rrow = p * 8 + (lane >> 3);
    const int colb = (lane & 7) * 8;
    uint4 v = *(const uint4*)(epi + rrow * 72 + colb);
    *(uint4*)(out + (orow0 + rrow) * C2 + n0 + colb) = v;
  }
}

// ---------------------------------------------------------------------------
__global__ __launch_bounds__(256) void glu_bn_k(
    const u16* __restrict__ hc, const float* __restrict__ bg,
    const float* __restrict__ bb_, const float* __restrict__ bm,
    const float* __restrict__ bv, u16* __restrict__ out) {
  const int idx = blockIdx.x * 256 + threadIdx.x;
  const int r  = idx >> 6;
  const int c8 = (idx & 63) * 8;
  const u16* pa = hc + (size_t)r * C2 + c8;
  uint4 ra = *(const uint4*)pa;
  uint4 rg = *(const uint4*)(pa + CC);
  u16 av[8], gv[8], ov[8];
  *(uint4*)av = ra; *(uint4*)gv = rg;
#pragma unroll
  for (int j = 0; j < 8; j++) {
    const int c = c8 + j;
    const float a = bf2f(av[j]);
    const float g = bf2f(gv[j]);
    const float h = a / (1.f + __expf(-g));
    const float sc = bg[c] * rsqrtf(bv[c] + 1e-5f);
    ov[j] = f2bf((h - bm[c]) * sc + bb_[c]);
  }
  *(uint4*)(out + (size_t)r * CC + c8) = *(const uint4*)ov;
}

// ---------------------------------------------------------------------------
extern "C" void kernel_launch(void* const* d_in, const int* in_sizes, int n_in,
                              void* d_out, int out_size, void* d_ws, size_t ws_size,
                              hipStream_t stream) {
  const float* x   = (const float*)d_in[0];
  const float* lng = (const float*)d_in[1];
  const float* lnb = (const float*)d_in[2];
  const float* w1  = (const float*)d_in[3];
  const float* b1  = (const float*)d_in[4];
  const float* w2  = (const float*)d_in[5];
  const float* b2  = (const float*)d_in[6];
  const float* bng = (const float*)d_in[7];
  const float* bnb = (const float*)d_in[8];
  const float* bnm = (const float*)d_in[9];
  const float* bnv = (const float*)d_in[10];
  const float* w3  = (const float*)d_in[11];
  const float* b3  = (const float*)d_in[12];

  u16* ws  = (u16*)d_ws;
  u16* hln = ws;                               // 16384*512
  u16* h2  = hln;                              // alias (hln dead after GEMM1)
  u16* h1p = ws + 8388608;                     // 16*1028*1024
  u16* w2t = h1p + 16842752;                   // 5*1024*1024
  u16* hcv = w2t + 5242880;                    // 16384*1024
  u16* w1b = hcv + 16777216;                   // 1024*512
  u16* w3b = w1b + 524288;                     // 512*512

  prep_k      <<<800, 256, 0, stream>>>(w1, w1b, w3, w3b, h1p);
  transpose_w2<<<dim3(16, 16, 5), dim3(64, 4), 0, stream>>>(w2, w2t);
  layernorm_k <<<4096, 256, 0, stream>>>(x, lng, lnb, hln);
  gemm_bt<0>  <<<dim3(4, 256), 256, 0, stream>>>(hln, w1b, b1, h1p, 512, 512);
  conv5_mfma  <<<dim3(4, 256), 256, 0, stream>>>(h1p, w2t, b2, hcv);
  glu_bn_k    <<<4096, 256, 0, stream>>>(hcv, bng, bnb, bnm, bnv, h2);
  gemm_bt<1>  <<<dim3(2, 256), 256, 0, stream>>>(h2, w3b, b3, d_out, 512, 512);
}

// Round 7
// 506.032 us; speedup vs baseline: 1.5675x; 1.5675x over previous
//
#include <hip/hip_runtime.h>
#include <cstdint>

// ---------------------------------------------------------------------------
// ConvModule: LN -> GEMM(512->1024)+SiLU -> conv K=5 (1024->1024) -> GLU ->
//             BN -> GEMM(512->512).  B=16, T=1024, C=512. fp32 I/O, bf16 MFMA.
// Round 7: R4 structure (A in LDS, B direct) + depth-2 named B prefetch
// (spill-safe per R6) + XCD-pinned n-slices (grid x = n-tile so each XCD's
// L2 holds one 1.3MB w2t slice).  Lessons: frag loads from global cost ~16
// line-cycles each (16-line span) -> keep A in LDS; >2-deep reg prefetch
// spills (R5); direct-global-everything is TCP-bound (R6).
// ---------------------------------------------------------------------------

#define NB    16
#define TT    1024
#define CC    512
#define C2    1024
#define TPAD  1028        // T + 4 pad rows (2 each side) per batch

typedef unsigned short u16;
typedef short bf16x8 __attribute__((ext_vector_type(8)));
typedef float f32x4  __attribute__((ext_vector_type(4)));

__device__ __forceinline__ float bf2f(u16 u) {
  union { unsigned int i; float f; } v; v.i = ((unsigned int)u) << 16; return v.f;
}
__device__ __forceinline__ u16 f2bf(float f) {
  union { float f; unsigned int i; } v; v.f = f;
  unsigned int x = v.i;
  return (u16)((x + 0x7fffu + ((x >> 16) & 1u)) >> 16);  // RNE
}

// ---------------------------------------------------------------------------
// prep: cvt w1 (fp32->bf16), cvt w3, zero h1p pad rows — one launch
__global__ __launch_bounds__(256) void prep_k(
    const float* __restrict__ w1, u16* __restrict__ w1b,
    const float* __restrict__ w3, u16* __restrict__ w3b,
    u16* __restrict__ h1p) {
  const int b = blockIdx.x;
  if (b < 512) {                       // w1: 524288 elems
    const int i = (b * 256 + threadIdx.x) * 4;
    float4 v = *(const float4*)(w1 + i);
    u16 o[4] = { f2bf(v.x), f2bf(v.y), f2bf(v.z), f2bf(v.w) };
    *(uint2*)(w1b + i) = *(const uint2*)o;
  } else if (b < 768) {                // w3: 262144 elems
    const int i = ((b - 512) * 256 + threadIdx.x) * 4;
    float4 v = *(const float4*)(w3 + i);
    u16 o[4] = { f2bf(v.x), f2bf(v.y), f2bf(v.z), f2bf(v.w) };
    *(uint2*)(w3b + i) = *(const uint2*)o;
  } else {                             // zero pads
    const int idx = (b - 768) * 256 + threadIdx.x;
    const int bb  = idx >> 9;
    const int rem = idx & 511;
    const int ri  = rem >> 7;
    const int c8  = (rem & 127) * 8;
    const int row = bb * TPAD + (ri < 2 ? ri : 1024 + ri);   // 0,1,1026,1027
    uint4 z = make_uint4(0u, 0u, 0u, 0u);
    *(uint4*)(h1p + (size_t)row * C2 + c8) = z;
  }
}

// ---------------------------------------------------------------------------
// w2 fp32 (K, I, O) -> w2t bf16 (K, O, I)
__global__ void transpose_w2(const float* __restrict__ w2, u16* __restrict__ w2t) {
  __shared__ u16 t[64][65];
  const int k  = blockIdx.z;
  const int i0 = blockIdx.x * 64, o0 = blockIdx.y * 64;
  const int tx = threadIdx.x, ty = threadIdx.y;
  for (int r = ty; r < 64; r += 4)
    t[r][tx] = f2bf(w2[((size_t)(k * C2) + i0 + r) * C2 + o0 + tx]);
  __syncthreads();
  for (int r = ty; r < 64; r += 4)
    w2t[((size_t)(k * C2) + o0 + r) * C2 + i0 + tx] = t[tx][r];
}

// ---------------------------------------------------------------------------
__global__ __launch_bounds__(256) void layernorm_k(
    const float* __restrict__ x, const float* __restrict__ lng,
    const float* __restrict__ lnb, u16* __restrict__ out) {
  const int tok  = blockIdx.x * 4 + (threadIdx.x >> 6);
  const int lane = threadIdx.x & 63;
  const float* xp = x + (size_t)tok * CC + lane * 8;
  float f[8];
  *(float4*)(f)     = *(const float4*)(xp);
  *(float4*)(f + 4) = *(const float4*)(xp + 4);
  float s = 0.f, s2 = 0.f;
#pragma unroll
  for (int j = 0; j < 8; j++) { s += f[j]; s2 += f[j] * f[j]; }
#pragma unroll
  for (int m = 32; m >= 1; m >>= 1) { s += __shfl_xor(s, m, 64); s2 += __shfl_xor(s2, m, 64); }
  const float mu  = s  * (1.f / 512.f);
  const float var = s2 * (1.f / 512.f) - mu * mu;
  const float rs  = rsqrtf(var + 1e-5f);
  u16 ov[8];
#pragma unroll
  for (int j = 0; j < 8; j++) {
    const int c = lane * 8 + j;
    ov[j] = f2bf((f[j] - mu) * rs * lng[c] + lnb[c]);
  }
  *(uint4*)(out + (size_t)tok * CC + lane * 8) = *(const uint4*)ov;
}

// ---------------------------------------------------------------------------
// GEMM out[m,n] = sum_k A[m,k]*Bt[n,k] + bias[n].  128x128 tile, BK=32.
// grid: x = n-tile (XCD pin), y = m-tile.  A: LDS double-buffered (stride 40).
// B: direct global, depth-2 named prefetch (Bf[2][4], compile-time slots).
// EPI 0: SiLU, bf16 -> h1p padded rows.  EPI 1: fp32 -> out (ld CC).
template <int EPI>
__global__ __launch_bounds__(256, 2) void gemm_bt(
    const u16* __restrict__ A, const u16* __restrict__ Bt,
    const float* __restrict__ bias, void* __restrict__ outv,
    const int Kd, const int ldA) {
  __shared__ __align__(16) u16 smem[18432];   // loop: 2x5120 | epi: 4x4608
  const int tid  = threadIdx.x;
  const int n0   = blockIdx.x * 128;          // x fastest -> XCD = n-tile
  const int m0   = blockIdx.y * 128;
  const int wave = tid >> 6, lane = tid & 63;
  const int wm = (wave & 1) * 64, wn = (wave >> 1) * 64;
  const int quad = lane >> 4, l16 = lane & 15;
  const int row = tid >> 2;            // 0..63
  const int kc  = (tid & 3) * 8;       // 0/8/16/24
  const int J = Kd >> 5;               // 16

  const u16* Ap0 = A + (size_t)(m0 + row) * ldA + kc;
  const u16* Ap1 = Ap0 + (size_t)64 * ldA;
  const u16* Bp  = Bt + (size_t)(n0 + wn + l16) * Kd + quad * 8;

  f32x4 acc[4][4] = {};
  uint4 rA0 = *(const uint4*)Ap0;
  uint4 rA1 = *(const uint4*)Ap1;
  *(uint4*)(smem + row * 40 + kc)        = rA0;
  *(uint4*)(smem + (64 + row) * 40 + kc) = rA1;
  rA0 = *(const uint4*)(Ap0 + 32);       // chunk 1
  rA1 = *(const uint4*)(Ap1 + 32);
  bf16x8 Bf[2][4];
#pragma unroll
  for (int i = 0; i < 4; i++) Bf[0][i] = *(const bf16x8*)(Bp + (size_t)i * 16 * Kd);
#pragma unroll
  for (int i = 0; i < 4; i++) Bf[1][i] = *(const bf16x8*)(Bp + (size_t)i * 16 * Kd + 32);

#pragma unroll 1
  for (int jj = 0; jj < J; jj += 2) {
#pragma unroll
    for (int h = 0; h < 2; h++) {              // j = jj+h, slot = h
      const int j  = jj + h;
      const int k0 = j * 32;
      __syncthreads();
      const u16* cur = smem + (h & 1) * 5120;  // (j&1)==h
      if (j + 1 < J) {
        u16* nxt = smem + ((h + 1) & 1) * 5120;
        *(uint4*)(nxt + row * 40 + kc)        = rA0;
        *(uint4*)(nxt + (64 + row) * 40 + kc) = rA1;
        if (j + 2 < J) {
          rA0 = *(const uint4*)(Ap0 + k0 + 64);
          rA1 = *(const uint4*)(Ap1 + k0 + 64);
        }
      }
      bf16x8 af[4];
#pragma unroll
      for (int i = 0; i < 4; i++)
        af[i] = *(const bf16x8*)(cur + (wm + i * 16 + l16) * 40 + quad * 8);
#pragma unroll
      for (int mi = 0; mi < 4; mi++)
#pragma unroll
        for (int ni = 0; ni < 4; ni++)
          acc[mi][ni] = __builtin_amdgcn_mfma_f32_16x16x32_bf16(
              af[mi], Bf[h][ni], acc[mi][ni], 0, 0, 0);
      const int k2 = (j + 2 < J) ? k0 + 64 : 0;   // clamped tail prefetch
#pragma unroll
      for (int i = 0; i < 4; i++)
        Bf[h][i] = *(const bf16x8*)(Bp + (size_t)i * 16 * Kd + k2);
    }
  }
  __syncthreads();

  float bv[4];
#pragma unroll
  for (int ni = 0; ni < 4; ni++) bv[ni] = bias[n0 + wn + ni * 16 + l16];

  if (EPI == 0) {
    u16* epi = smem + wave * 4608;       // 64 x 72 u16, private
#pragma unroll
    for (int mi = 0; mi < 4; mi++)
#pragma unroll
      for (int ni = 0; ni < 4; ni++)
#pragma unroll
        for (int r = 0; r < 4; r++) {
          float v = acc[mi][ni][r] + bv[ni];
          v = v / (1.f + __expf(-v));    // SiLU
          epi[(mi * 16 + quad * 4 + r) * 72 + ni * 16 + l16] = f2bf(v);
        }
    u16* h1p = (u16*)outv;
#pragma unroll
    for (int p = 0; p < 8; p++) {
      const int rrow = p * 8 + (lane >> 3);
      const int colb = (lane & 7) * 8;
      uint4 v = *(const uint4*)(epi + rrow * 72 + colb);
      const int rr = m0 + wm + rrow;
      const int bb = rr >> 10, tt = rr & 1023;
      *(uint4*)(h1p + (size_t)(bb * TPAD + tt + 2) * C2 + n0 + wn + colb) = v;
    }
  } else {
    float* fepi = (float*)(smem + wave * 4608);   // 2 x (16 x 68) f32
    float* outf = (float*)outv;
#pragma unroll
    for (int mi = 0; mi < 4; mi++) {
      float* fp = fepi + (mi & 1) * 1088;
#pragma unroll
      for (int ni = 0; ni < 4; ni++)
#pragma unroll
        for (int r = 0; r < 4; r++)
          fp[(quad * 4 + r) * 68 + ni * 16 + l16] = acc[mi][ni][r] + bv[ni];
#pragma unroll
      for (int p = 0; p < 4; p++) {
        const int rrow = p * 4 + (lane >> 4);
        const int col  = (lane & 15) * 4;
        float4 v = *(const float4*)(fp + rrow * 68 + col);
        *(float4*)(outf + (size_t)(m0 + wm + mi * 16 + rrow) * CC + n0 + wn + col) = v;
      }
    }
  }
}

// ---------------------------------------------------------------------------
// 5-tap conv: A (h1p) 132x32 LDS double-buffered (stride 40), B direct global
// with depth-2 stage rotation over s = j*5+k (prefetch s+2, ~500cyc cover).
// grid: x = n-tile (XCD pin -> each XCD L2 holds one 1.3MB w2t slice).
__global__ __launch_bounds__(256, 2) void conv5_mfma(
    const u16* __restrict__ h1p, const u16* __restrict__ w2t,
    const float* __restrict__ b2, u16* __restrict__ out) {
  __shared__ __align__(16) u16 smem[18432];   // loop: 2x5280 | epi: 4x4608
  const int tid = threadIdx.x;
  const int n0  = blockIdx.x * 128;           // x fastest -> XCD = n-tile
  const int mt  = blockIdx.y;                 // 0..127
  const int bb  = mt >> 3;
  const int t0  = (mt & 7) * 128;
  const size_t arow0 = (size_t)bb * TPAD + t0;
  const int wave = tid >> 6, lane = tid & 63;
  const int wm = (wave & 1) * 64, wn = (wave >> 1) * 64;
  const int quad = lane >> 4, l16 = lane & 15;
  const int row = tid >> 2;
  const int kc  = (tid & 3) * 8;

  const u16* Ap0 = h1p + (arow0 + row) * C2 + kc;
  const u16* Ap1 = Ap0 + (size_t)64 * C2;
  const u16* Ap2 = h1p + (arow0 + 128 + row) * C2 + kc;   // tid<16: rows 128..131
  const u16* Bb  = w2t + (size_t)(n0 + wn + l16) * C2 + quad * 8;

  f32x4 acc[4][4] = {};
  uint4 rA0 = *(const uint4*)Ap0;
  uint4 rA1 = *(const uint4*)Ap1;
  uint4 rA2;
  if (tid < 16) rA2 = *(const uint4*)Ap2;
  *(uint4*)(smem + row * 40 + kc)        = rA0;
  *(uint4*)(smem + (64 + row) * 40 + kc) = rA1;
  if (tid < 16) *(uint4*)(smem + (128 + row) * 40 + kc) = rA2;
  rA0 = *(const uint4*)(Ap0 + 32);       // chunk 1
  rA1 = *(const uint4*)(Ap1 + 32);
  if (tid < 16) rA2 = *(const uint4*)(Ap2 + 32);
  bf16x8 Bf[2][4];                       // stage s=0 (tap0,c0), s=1 (tap1,c0)
#pragma unroll
  for (int i = 0; i < 4; i++)
    Bf[0][i] = *(const bf16x8*)(Bb + (size_t)i * 16 * C2);
#pragma unroll
  for (int i = 0; i < 4; i++)
    Bf[1][i] = *(const bf16x8*)(Bb + (size_t)C2 * C2 + (size_t)i * 16 * C2);

#pragma unroll 1
  for (int jj = 0; jj < 32; jj += 2) {
#pragma unroll
    for (int h = 0; h < 2; h++) {              // j = jj+h
      const int j  = jj + h;
      const int i0 = j * 32;
      __syncthreads();
      const u16* cur = smem + (h & 1) * 5280;  // (j&1)==h
      if (j + 1 < 32) {
        u16* nxt = smem + ((h + 1) & 1) * 5280;
        *(uint4*)(nxt + row * 40 + kc)        = rA0;
        *(uint4*)(nxt + (64 + row) * 40 + kc) = rA1;
        if (tid < 16) *(uint4*)(nxt + (128 + row) * 40 + kc) = rA2;
        if (j + 2 < 32) {
          rA0 = *(const uint4*)(Ap0 + i0 + 64);
          rA1 = *(const uint4*)(Ap1 + i0 + 64);
          if (tid < 16) rA2 = *(const uint4*)(Ap2 + i0 + 64);
        }
      }
#pragma unroll
      for (int k = 0; k < 5; k++) {            // stage s = j*5+k, slot (h+k)&1
        const int slot = (h + k) & 1;
        bf16x8 af[4];
#pragma unroll
        for (int i = 0; i < 4; i++)
          af[i] = *(const bf16x8*)(cur + (wm + i * 16 + l16 + k) * 40 + quad * 8);
#pragma unroll
        for (int mi = 0; mi < 4; mi++)
#pragma unroll
          for (int ni = 0; ni < 4; ni++)
            acc[mi][ni] = __builtin_amdgcn_mfma_f32_16x16x32_bf16(
                af[mi], Bf[slot][ni], acc[mi][ni], 0, 0, 0);
        // prefetch stage s+2 into just-consumed slot
        const int k2 = (k < 3) ? k + 2 : k - 3;
        const int j2 = (k < 3) ? j : j + 1;
        const int io2 = (j2 < 32) ? j2 * 32 : 0;   // clamped tail
#pragma unroll
        for (int i = 0; i < 4; i++)
          Bf[slot][i] = *(const bf16x8*)(Bb + (size_t)k2 * C2 * C2 +
                                         (size_t)i * 16 * C2 + io2);
      }
    }
  }
  __syncthreads();

  float bv[4];
#pragma unroll
  for (int ni = 0; ni < 4; ni++) bv[ni] = b2[n0 + wn + ni * 16 + l16];

  u16* epi = smem + wave * 4608;         // 64 x 72 u16, private
#pragma unroll
  for (int mi = 0; mi < 4; mi++)
#pragma unroll
    for (int ni = 0; ni < 4; ni++)
#pragma unroll
      for (int r = 0; r < 4; r++)
        epi[(mi * 16 + quad * 4 + r) * 72 + ni * 16 + l16] = f2bf(acc[mi][ni][r] + bv[ni]);

  const size_t orow0 = (size_t)bb * TT + t0;
#pragma unroll
  for (int p = 0; p < 8; p++) {
    const int rrow = p * 8 + (lane >> 3);
    const int colb = (lane & 7) * 8;
    uint4 v = *(const uint4*)(epi + rrow * 72 + colb);
    *(uint4*)(out + (orow0 + wm + rrow) * C2 + n0 + wn + colb) = v;
  }
}

// ---------------------------------------------------------------------------
__global__ __launch_bounds__(256) void glu_bn_k(
    const u16* __restrict__ hc, const float* __restrict__ bg,
    const float* __restrict__ bb_, const float* __restrict__ bm,
    const float* __restrict__ bv, u16* __restrict__ out) {
  const int idx = blockIdx.x * 256 + threadIdx.x;
  const int r  = idx >> 6;
  const int c8 = (idx & 63) * 8;
  const u16* pa = hc + (size_t)r * C2 + c8;
  uint4 ra = *(const uint4*)pa;
  uint4 rg = *(const uint4*)(pa + CC);
  u16 av[8], gv[8], ov[8];
  *(uint4*)av = ra; *(uint4*)gv = rg;
#pragma unroll
  for (int j = 0; j < 8; j++) {
    const int c = c8 + j;
    const float a = bf2f(av[j]);
    const float g = bf2f(gv[j]);
    const float h = a / (1.f + __expf(-g));
    const float sc = bg[c] * rsqrtf(bv[c] + 1e-5f);
    ov[j] = f2bf((h - bm[c]) * sc + bb_[c]);
  }
  *(uint4*)(out + (size_t)r * CC + c8) = *(const uint4*)ov;
}

// ---------------------------------------------------------------------------
extern "C" void kernel_launch(void* const* d_in, const int* in_sizes, int n_in,
                              void* d_out, int out_size, void* d_ws, size_t ws_size,
                              hipStream_t stream) {
  const float* x   = (const float*)d_in[0];
  const float* lng = (const float*)d_in[1];
  const float* lnb = (const float*)d_in[2];
  const float* w1  = (const float*)d_in[3];
  const float* b1  = (const float*)d_in[4];
  const float* w2  = (const float*)d_in[5];
  const float* b2  = (const float*)d_in[6];
  const float* bng = (const float*)d_in[7];
  const float* bnb = (const float*)d_in[8];
  const float* bnm = (const float*)d_in[9];
  const float* bnv = (const float*)d_in[10];
  const float* w3  = (const float*)d_in[11];
  const float* b3  = (const float*)d_in[12];

  u16* ws  = (u16*)d_ws;
  u16* hln = ws;                               // 16384*512
  u16* h2  = hln;                              // alias (hln dead after GEMM1)
  u16* h1p = ws + 8388608;                     // 16*1028*1024
  u16* w2t = h1p + 16842752;                   // 5*1024*1024
  u16* hcv = w2t + 5242880;                    // 16384*1024
  u16* w1b = hcv + 16777216;                   // 1024*512
  u16* w3b = w1b + 524288;                     // 512*512

  prep_k      <<<800, 256, 0, stream>>>(w1, w1b, w3, w3b, h1p);
  transpose_w2<<<dim3(16, 16, 5), dim3(64, 4), 0, stream>>>(w2, w2t);
  layernorm_k <<<4096, 256, 0, stream>>>(x, lng, lnb, hln);
  gemm_bt<0>  <<<dim3(8, 128), 256, 0, stream>>>(hln, w1b, b1, h1p, 512, 512);
  conv5_mfma  <<<dim3(8, 128), 256, 0, stream>>>(h1p, w2t, b2, hcv);
  glu_bn_k    <<<4096, 256, 0, stream>>>(hcv, bng, bnb, bnm, bnv, h2);
  gemm_bt<1>  <<<dim3(4, 128), 256, 0, stream>>>(h2, w3b, b3, d_out, 512, 512);
}